// Round 1
// baseline (5792.511 us; speedup 1.0000x reference)
//
#include <hip/hip_runtime.h>
#include <stdint.h>

// FastGCNConv: gumbel-top-k sample 100K of 500K rows, gathered GEMM [S,256]x[256,256],
// scaled scatter into zeroed [N,256] output.
//
// Correctness-critical: reproduce jax.random.gumbel(jax.random.key(42), (N,)) bit-exactly.
// PARTITIONABLE=1 -> modern JAX default (threefry_partitionable): bits[i] = v0^v1 of
//   threefry2x32(key=(0,42), x=(0,i)).
// PARTITIONABLE=0 -> legacy: counts=iota(N) split in halves, pair (i, i+N/2).
// If round fails verification, flip this first; then investigate logf vs XLA log.
#define PARTITIONABLE 1

#define NN 500000
#define INC 256
#define OUTC 256
#define SS 100000
#define OUT_SCALE 5.0f   // N/S

struct Ctrl {
  unsigned hist[1024];   // 4 passes x 256 bins
  unsigned prefix;       // accumulated radix prefix; after pass 3 == threshold key T
  unsigned need;         // remaining count to take among elements == current prefix
  unsigned sel_count;
  unsigned unsel_count;
  unsigned eq_count;
};

__device__ __forceinline__ void threefry2x32(unsigned k0, unsigned k1,
                                             unsigned& x0, unsigned& x1) {
  const unsigned ks2 = k0 ^ k1 ^ 0x1BD11BDAu;
  x0 += k0; x1 += k1;
#define TF_RND(R) { x0 += x1; x1 = (x1 << (R)) | (x1 >> (32 - (R))); x1 ^= x0; }
  TF_RND(13) TF_RND(15) TF_RND(26) TF_RND(6)
  x0 += k1; x1 += ks2 + 1u;
  TF_RND(17) TF_RND(29) TF_RND(16) TF_RND(24)
  x0 += ks2; x1 += k0 + 2u;
  TF_RND(13) TF_RND(15) TF_RND(26) TF_RND(6)
  x0 += k0; x1 += k1 + 3u;
  TF_RND(17) TF_RND(29) TF_RND(16) TF_RND(24)
  x0 += k1; x1 += ks2 + 4u;
  TF_RND(13) TF_RND(15) TF_RND(26) TF_RND(6)
  x0 += ks2; x1 += k0 + 5u;
#undef TF_RND
}

// score[i] = log(p[i]) + gumbel[i]; store as monotone-sortable u32 key.
__global__ void score_kernel(const float* __restrict__ p, unsigned* __restrict__ keys,
                             Ctrl* __restrict__ ctrl) {
  if (blockIdx.x == 0) {
    for (int h = threadIdx.x; h < 1024; h += 256) ctrl->hist[h] = 0;
    if (threadIdx.x == 0) {
      ctrl->prefix = 0u; ctrl->need = SS;
      ctrl->sel_count = 0u; ctrl->unsel_count = 0u; ctrl->eq_count = 0u;
    }
  }
  int i = blockIdx.x * 256 + threadIdx.x;
  if (i >= NN) return;

  unsigned bits;
#if PARTITIONABLE
  unsigned x0 = 0u, x1 = (unsigned)i;
  threefry2x32(0u, 42u, x0, x1);
  bits = x0 ^ x1;
#else
  int j = (i < NN / 2) ? i : i - NN / 2;
  unsigned x0 = (unsigned)j, x1 = (unsigned)(j + NN / 2);
  threefry2x32(0u, 42u, x0, x1);
  bits = (i < NN / 2) ? x0 : x1;
#endif

  // JAX uniform(minval=tiny, maxval=1): u in [0,1) from mantissa bits; the
  // f32 arithmetic u*(1-tiny)+tiny reduces exactly to (u==0 ? tiny : u).
  float u = __uint_as_float((bits >> 9) | 0x3F800000u) - 1.0f;
  float val = (u == 0.0f) ? 1.1754943508222875e-38f : u;
  float g = -logf(-logf(val));
  float s = logf(p[i]) + g;

  unsigned b = __float_as_uint(s);
  unsigned key = b ^ ((b & 0x80000000u) ? 0xFFFFFFFFu : 0x80000000u);
  keys[i] = key;
}

__global__ void hist_kernel(const unsigned* __restrict__ keys, Ctrl* __restrict__ ctrl,
                            int pass) {
  __shared__ unsigned lh[256];
  lh[threadIdx.x] = 0u;
  __syncthreads();
  const unsigned prefix = ctrl->prefix;
  const int stride = gridDim.x * 256;
  for (int i = blockIdx.x * 256 + threadIdx.x; i < NN; i += stride) {
    unsigned k = keys[i];
    bool m = (pass == 0) || ((k >> (8 * (4 - pass))) == prefix);
    if (m) atomicAdd(&lh[(k >> (8 * (3 - pass))) & 0xFFu], 1u);
  }
  __syncthreads();
  unsigned c = lh[threadIdx.x];
  if (c) atomicAdd(&ctrl->hist[pass * 256 + threadIdx.x], c);
}

__global__ void scan_kernel(Ctrl* __restrict__ ctrl, int pass) {
  if (threadIdx.x != 0 || blockIdx.x != 0) return;
  unsigned need = ctrl->need;
  const unsigned* h = &ctrl->hist[pass * 256];
  unsigned cum = 0u;
  int b = 255;
  for (; b > 0; --b) {
    unsigned c = h[b];
    if (cum + c >= need) break;
    cum += c;
  }
  ctrl->need = need - cum;
  ctrl->prefix = (ctrl->prefix << 8) | (unsigned)b;
}

__global__ void select_kernel(const unsigned* __restrict__ keys, Ctrl* __restrict__ ctrl,
                              int* __restrict__ sel, int* __restrict__ unsel,
                              int* __restrict__ eq) {
  int i = blockIdx.x * 256 + threadIdx.x;
  if (i >= NN) return;
  const unsigned T = ctrl->prefix;
  unsigned k = keys[i];
  if (k > T) {
    sel[atomicAdd(&ctrl->sel_count, 1u)] = i;
  } else if (k < T) {
    unsel[atomicAdd(&ctrl->unsel_count, 1u)] = i;
  } else {
    unsigned q = atomicAdd(&ctrl->eq_count, 1u);
    if (q < 4096u) eq[q] = i;   // ties at threshold: tiny in practice
  }
}

// lax.top_k tie-break: lowest indices win among equal values.
__global__ void eq_resolve_kernel(Ctrl* __restrict__ ctrl, int* __restrict__ sel,
                                  int* __restrict__ unsel, const int* __restrict__ eq) {
  unsigned n = ctrl->eq_count; if (n > 4096u) n = 4096u;
  const unsigned need = ctrl->need;
  for (unsigned j = threadIdx.x; j < n; j += 256) {
    int idx = eq[j];
    unsigned rank = 0u;
    for (unsigned l = 0; l < n; ++l) rank += (eq[l] < idx) ? 1u : 0u;
    if (rank < need) sel[atomicAdd(&ctrl->sel_count, 1u)] = idx;
    else             unsel[atomicAdd(&ctrl->unsel_count, 1u)] = idx;
  }
}

// one wave zeroes one 1KB row per iteration (64 lanes x float4)
__global__ void zero_kernel(float* __restrict__ out, const int* __restrict__ unsel) {
  int wid = blockIdx.x * 4 + (threadIdx.x >> 6);
  int lane = threadIdx.x & 63;
  const int nuns = NN - SS;
  for (int j = wid; j < nuns; j += gridDim.x * 4) {
    int row = unsel[j];
    *(float4*)(out + (size_t)row * OUTC + lane * 4) = make_float4(0.f, 0.f, 0.f, 0.f);
  }
}

// 64 rows x 256 cols per block; 256 threads; thread tile 16 rows x 4 cols.
// X reads from LDS are wave-uniform (broadcast); W reads are stride-16B b128.
__global__ __launch_bounds__(256) void gemm_kernel(const float* __restrict__ x,
    const float* __restrict__ w, const float* __restrict__ bias,
    const int* __restrict__ sel, float* __restrict__ out) {
  __shared__ __align__(16) float Xt[64][32];
  __shared__ __align__(16) float Wt[32][256];
  const int t = threadIdx.x;
  const int tcol = t & 63;   // cols tcol*4 .. +3
  const int trow = t >> 6;   // rows trow*16 .. +15
  const int row_base = blockIdx.x * 64;

  float acc[16][4];
  const float4 b4 = *(const float4*)(bias + tcol * 4);
  #pragma unroll
  for (int r = 0; r < 16; ++r) { acc[r][0]=b4.x; acc[r][1]=b4.y; acc[r][2]=b4.z; acc[r][3]=b4.w; }

  for (int kb = 0; kb < INC; kb += 32) {
    #pragma unroll
    for (int q = 0; q < 8; ++q) {           // stage W[32][256]
      int l = q * 256 + t;
      int kk = l >> 6, c4 = l & 63;
      *(float4*)&Wt[kk][c4 * 4] = *(const float4*)(w + (size_t)(kb + kk) * OUTC + c4 * 4);
    }
    #pragma unroll
    for (int q = 0; q < 2; ++q) {           // stage X[64][32] (gathered rows)
      int l = q * 256 + t;
      int r = l >> 3, c4 = l & 7;
      int gr = row_base + r;
      float4 v = make_float4(0.f, 0.f, 0.f, 0.f);
      if (gr < SS) {
        int srow = sel[gr];
        v = *(const float4*)(x + (size_t)srow * INC + kb + c4 * 4);
      }
      *(float4*)&Xt[r][c4 * 4] = v;
    }
    __syncthreads();
    #pragma unroll
    for (int k0 = 0; k0 < 32; k0 += 4) {
      float wreg[4][4];
      #pragma unroll
      for (int jj = 0; jj < 4; ++jj) {
        float4 t4 = *(const float4*)&Wt[k0 + jj][tcol * 4];
        wreg[jj][0]=t4.x; wreg[jj][1]=t4.y; wreg[jj][2]=t4.z; wreg[jj][3]=t4.w;
      }
      #pragma unroll
      for (int rr = 0; rr < 16; ++rr) {
        float4 xv = *(const float4*)&Xt[trow * 16 + rr][k0];
        float xr[4] = {xv.x, xv.y, xv.z, xv.w};
        #pragma unroll
        for (int jj = 0; jj < 4; ++jj) {
          acc[rr][0] += xr[jj] * wreg[jj][0];
          acc[rr][1] += xr[jj] * wreg[jj][1];
          acc[rr][2] += xr[jj] * wreg[jj][2];
          acc[rr][3] += xr[jj] * wreg[jj][3];
        }
      }
    }
    __syncthreads();
  }
  #pragma unroll
  for (int rr = 0; rr < 16; ++rr) {
    int gr = row_base + trow * 16 + rr;
    if (gr < SS) {
      int srow = sel[gr];
      float4 o = make_float4(acc[rr][0]*OUT_SCALE, acc[rr][1]*OUT_SCALE,
                             acc[rr][2]*OUT_SCALE, acc[rr][3]*OUT_SCALE);
      *(float4*)(out + (size_t)srow * OUTC + tcol * 4) = o;
    }
  }
}

extern "C" void kernel_launch(void* const* d_in, const int* in_sizes, int n_in,
                              void* d_out, int out_size, void* d_ws, size_t ws_size,
                              hipStream_t stream) {
  (void)in_sizes; (void)n_in; (void)out_size; (void)ws_size;
  const float* x    = (const float*)d_in[0];
  const float* w    = (const float*)d_in[1];
  const float* bias = (const float*)d_in[2];
  const float* p    = (const float*)d_in[3];
  // d_in[4] = edge_index, unused by the sampled branch
  float* out = (float*)d_out;

  // ws layout (~4.1 MB): keys[N] u32 | Ctrl | sel[S] | unsel[N-S] | eq[4096]
  uint8_t* ws = (uint8_t*)d_ws;
  unsigned* keys = (unsigned*)ws;
  Ctrl* ctrl = (Ctrl*)(ws + (size_t)NN * 4);
  int* sel   = (int*)(ctrl + 1);
  int* unsel = sel + SS;
  int* eq    = unsel + (NN - SS);

  score_kernel<<<(NN + 255) / 256, 256, 0, stream>>>(p, keys, ctrl);
  for (int pass = 0; pass < 4; ++pass) {
    hist_kernel<<<1024, 256, 0, stream>>>(keys, ctrl, pass);
    scan_kernel<<<1, 64, 0, stream>>>(ctrl, pass);
  }
  select_kernel<<<(NN + 255) / 256, 256, 0, stream>>>(keys, ctrl, sel, unsel, eq);
  eq_resolve_kernel<<<1, 256, 0, stream>>>(ctrl, sel, unsel, eq);
  zero_kernel<<<2048, 256, 0, stream>>>(out, unsel);
  gemm_kernel<<<(SS + 63) / 64, 256, 0, stream>>>(x, w, bias, sel, out);
}